// Round 3
// baseline (116.952 us; speedup 1.0000x reference)
//
#include <hip/hip_runtime.h>

// Fused GAT layer, bf16-MFMA, round 3.
// Changes vs R2: (1) W pre-transposed+converted to bf16 in d_ws by a prep kernel
// (kills 64 scalar loads + 64 f2bf per thread); (2) K-loop/epilogue split per
// n-row -> acc 16 regs, e/att merged in place -> peak ~110 VGPR, launch_bounds
// (256,4) => 4 blocks/CU.
// Layout (m89): acc[h][gt]: m = nl*32 + 16h + (lane>>4)*4 + r, g = 32wv + 16gt + (lane&15)
//   => n = n0+nl, k = 16h + (lane>>4)*4 + r.

#define NK 32768
#define NEG_SLOPE 0.2f

using f32x4 = __attribute__((ext_vector_type(4))) float;
using s16x8 = __attribute__((ext_vector_type(8))) short;

__device__ __forceinline__ unsigned short f2bf(float f) {   // RNE float->bf16
    unsigned u = __float_as_uint(f);
    return (unsigned short)((u + 0x7FFFu + ((u >> 16) & 1u)) >> 16);
}

// ---- prep: Wt[g][f] = bf16(W[f][g]), 128x128
__global__ __launch_bounds__(256) void prep_wt(
    const float* __restrict__ W, unsigned short* __restrict__ Wt)
{
    const int i = blockIdx.x * 256 + threadIdx.x;   // i = g*128 + f
    const int g = i >> 7, f = i & 127;
    Wt[i] = f2bf(W[f * 128 + g]);
}

__global__ __launch_bounds__(256, 4) void fused_gat_mfma(
    const float* __restrict__ x,
    const int*   __restrict__ core_types,
    const int*   __restrict__ target_types,
    const unsigned short* __restrict__ Wt,   // bf16 W^T [g][f]
    const float* __restrict__ a_pair,
    float* __restrict__ out,
    float* __restrict__ att_out)
{
    __shared__ __align__(16) unsigned short xs[64 * 136];   // x^T tile bf16: [m][f], +8 pad

    const int t    = threadIdx.x;
    const int wv   = __builtin_amdgcn_readfirstlane(t >> 6);
    const int lane = t & 63;
    const int l15  = lane & 15;
    const int l4   = lane >> 4;
    const int b    = blockIdx.x >> 9;
    const int n0   = (blockIdx.x & 511) * 2;

    // ---- stage x^T tile as bf16 (transpose via packed b32 LDS writes)
    {
        const float* xb = x + (size_t)b * 128 * NK + (size_t)n0 * 32;
        const int m   = t & 63;
        const int fp0 = t >> 6;
        unsigned int* xs32 = (unsigned int*)xs;
        #pragma unroll
        for (int r = 0; r < 16; ++r) {
            const int fp = fp0 + r * 4;                     // f-pair 0..63
            const float lo = xb[(size_t)(2 * fp)     * NK + m];
            const float hi = xb[(size_t)(2 * fp + 1) * NK + m];
            xs32[m * 68 + fp] = (unsigned int)f2bf(lo) | ((unsigned int)f2bf(hi) << 16);
        }
    }

    // ---- B fragments: 8 x dwordx4 from bf16 W^T (L2-hot, no conversion)
    s16x8 bfrag[2][4];
    #pragma unroll
    for (int gt = 0; gt < 2; ++gt) {
        const unsigned short* wr = Wt + (wv * 32 + gt * 16 + l15) * 128 + l4 * 8;
        #pragma unroll
        for (int fs = 0; fs < 4; ++fs)
            bfrag[gt][fs] = *(const s16x8*)(wr + fs * 32);
    }

    const int c01[2] = { core_types[b * 1024 + n0], core_types[b * 1024 + n0 + 1] };

    __syncthreads();

    // ---- per n-row: MFMA + epilogue (keeps acc at 16 regs)
    #pragma unroll
    for (int nl = 0; nl < 2; ++nl) {
        const int n = n0 + nl;

        f32x4 acc[2][2];
        #pragma unroll
        for (int h = 0; h < 2; ++h)
            #pragma unroll
            for (int gt = 0; gt < 2; ++gt)
                acc[h][gt] = (f32x4){0.f, 0.f, 0.f, 0.f};

        #pragma unroll
        for (int fs = 0; fs < 4; ++fs) {
            s16x8 a0 = *(const s16x8*)&xs[(nl * 32 +      l15) * 136 + fs * 32 + l4 * 8];
            s16x8 a1 = *(const s16x8*)&xs[(nl * 32 + 16 + l15) * 136 + fs * 32 + l4 * 8];
            #pragma unroll
            for (int gt = 0; gt < 2; ++gt) {
                acc[0][gt] = __builtin_amdgcn_mfma_f32_16x16x32_bf16(a0, bfrag[gt][fs], acc[0][gt], 0, 0, 0);
                acc[1][gt] = __builtin_amdgcn_mfma_f32_16x16x32_bf16(a1, bfrag[gt][fs], acc[1][gt], 0, 0, 0);
            }
        }

        // e = leaky_relu(Wh * a) -> att (in place)
        const int cc = c01[nl];
        float ev[2][2][4];
        #pragma unroll
        for (int h = 0; h < 2; ++h) {
            const int kb = 16 * h + l4 * 4;
            const int4 tt4 = *(const int4*)&target_types[((size_t)(b * 1024 + n)) * 32 + kb];
            const int ttv[4] = {tt4.x, tt4.y, tt4.z, tt4.w};
            #pragma unroll
            for (int r = 0; r < 4; ++r) {
                const int tt = ttv[r];
                const int lo = min(cc, tt), hi = max(cc, tt);
                const int idx = lo * (17 - lo) / 2 + (hi - lo);
                const float* arow = a_pair + idx * 128 + wv * 32 + l15;
                #pragma unroll
                for (int gt = 0; gt < 2; ++gt) {
                    const float e = acc[h][gt][r] * arow[gt * 16];
                    ev[h][gt][r] = e > 0.f ? e : NEG_SLOPE * e;
                }
            }
        }

        // softmax over k (regs r + h, lanes xor 16/32)
        #pragma unroll
        for (int gt = 0; gt < 2; ++gt) {
            float mx = -1e30f;
            #pragma unroll
            for (int h = 0; h < 2; ++h)
                #pragma unroll
                for (int r = 0; r < 4; ++r) mx = fmaxf(mx, ev[h][gt][r]);
            mx = fmaxf(mx, __shfl_xor(mx, 16));
            mx = fmaxf(mx, __shfl_xor(mx, 32));
            float sm = 0.f;
            #pragma unroll
            for (int h = 0; h < 2; ++h)
                #pragma unroll
                for (int r = 0; r < 4; ++r) {
                    const float p = __expf(ev[h][gt][r] - mx);
                    ev[h][gt][r] = p;
                    sm += p;
                }
            sm += __shfl_xor(sm, 16);
            sm += __shfl_xor(sm, 32);
            const float inv = __fdividef(1.f, sm);
            #pragma unroll
            for (int h = 0; h < 2; ++h)
                #pragma unroll
                for (int r = 0; r < 4; ++r) ev[h][gt][r] *= inv;
        }

        // stores
        #pragma unroll
        for (int h = 0; h < 2; ++h) {
            const int kb = 16 * h + l4 * 4;
            #pragma unroll
            for (int gt = 0; gt < 2; ++gt) {
                const int g = wv * 32 + gt * 16 + l15;
                f32x4 ov;
                #pragma unroll
                for (int r = 0; r < 4; ++r) {
                    const float hh = ev[h][gt][r] * acc[h][gt][r];
                    ov[r] = hh > 0.f ? hh : __expf(hh) - 1.f;
                }
                *(f32x4*)&out[(size_t)b * 128 * NK + (size_t)g * NK + n * 32 + kb] = ov;
            }
            #pragma unroll
            for (int r = 0; r < 4; ++r) {
                const size_t abase = (((size_t)(b * 1024 + n)) * 32 + kb + r) * 128 + wv * 32 + l15;
                att_out[abase]      = ev[h][0][r];
                att_out[abase + 16] = ev[h][1][r];
            }
        }
    }
}

extern "C" void kernel_launch(void* const* d_in, const int* in_sizes, int n_in,
                              void* d_out, int out_size, void* d_ws, size_t ws_size,
                              hipStream_t stream) {
    const float* x    = (const float*)d_in[0];
    const int*   core = (const int*)  d_in[1];
    const int*   tgt  = (const int*)  d_in[2];
    const float* W    = (const float*)d_in[3];
    const float* ap   = (const float*)d_in[4];
    // d_in[5]/d_in[6] (lin_w, lin_b) only feed attention_viz, which is not returned.

    unsigned short* Wt = (unsigned short*)d_ws;         // 128*128 bf16 = 32 KB

    float* out_p = (float*)d_out;                       // (8,128,1024,32)
    float* att_p = out_p + (size_t)8 * 128 * 1024 * 32; // (8,1024,32,128)

    prep_wt<<<dim3(64), dim3(256), 0, stream>>>(W, Wt);
    fused_gat_mfma<<<dim3(4096), dim3(256), 0, stream>>>(x, core, tgt, Wt, ap, out_p, att_p);
}